// Round 13
// baseline (85.415 us; speedup 1.0000x reference)
//
#include <hip/hip_runtime.h>

#define BATCH 1024
#define INSZ 4096
#define NH 8
#define TPB 256

typedef __attribute__((ext_vector_type(8))) __bf16 bf16x8;
typedef __attribute__((ext_vector_type(4))) __bf16 bf16x4;
typedef __attribute__((ext_vector_type(4))) float f32x4;

// Per-row LDS block (bf16 elem offsets), two blocks at rr*ROWSZ:
//   Q0 [0,5120)       q-stage parity0 [128][LDT=40] (xn overlay pre-loop)
//   Q1 [5120,10240)   q-stage parity1
//   KP [10240,15360)  K-stage [128][LDT] — wave-local, consumed to regs in proj
//   V0 [15360,19456)  vT parity0 [32][128] swizzled
//   V1 [19456,23552)  vT parity1
//   PO [23552,39936)  P [128][128] swizzled — single buffer (A(h+1) separates)
//   RD [39936,39952)  LN reduction scratch
// ROWSZ = 39952 elems; 2 rows = 79904 elems = 159808 B -> 1 block/CU.
#define LDT 40
#define Q0 0
#define Q1 5120
#define KP 10240
#define V0 15360
#define V1 19456
#define PO 23552
#define RD 39936
#define ROWSZ 39952

// 1/sqrt(32) * log2(e): folded into wq (cvt_w) and bq seed; scores emerge
// pre-scaled for exp2. Softmax over QUERY axis uses m=0 (shift-invariant).
#define CQ 0.25505644061151687f

__global__ void cvt_w(const float* __restrict__ wq, const float* __restrict__ wk,
                      const float* __restrict__ wv, const float* __restrict__ wo,
                      __bf16* __restrict__ ws) {
  int i = blockIdx.x * blockDim.x + threadIdx.x;  // 0..32767
  const float* src = (i < 8192) ? wq : (i < 16384) ? wk : (i < 24576) ? wv : wo;
  float v = src[i & 8191];
  if (i < 8192) v *= CQ;
  ws[i] = (__bf16)v;
}

// 16-lane butterfly sum on the VALU pipe (DPP), no LDS traffic.
__device__ __forceinline__ float row_reduce_add16(float v) {
  int t;
  t = __builtin_amdgcn_update_dpp(0, __float_as_int(v), 0xB1, 0xF, 0xF, true);
  v += __int_as_float(t);
  t = __builtin_amdgcn_update_dpp(0, __float_as_int(v), 0x4E, 0xF, 0xF, true);
  v += __int_as_float(t);
  t = __builtin_amdgcn_update_dpp(0, __float_as_int(v), 0x141, 0xF, 0xF, true);
  v += __int_as_float(t);
  t = __builtin_amdgcn_update_dpp(0, __float_as_int(v), 0x140, 0xF, 0xF, true);
  v += __int_as_float(t);
  return v;
}

__global__ __launch_bounds__(TPB, 1) void mha_fused(
    const float* __restrict__ x, const float* __restrict__ gamma,
    const float* __restrict__ beta, const float* __restrict__ bq,
    const float* __restrict__ bk, const float* __restrict__ bv,
    const float* __restrict__ bo, const __bf16* __restrict__ wbf,
    float* __restrict__ out) {
  __shared__ __align__(16) __bf16 R[2 * ROWSZ];  // 159808 B

  const int b2 = blockIdx.x * 2;  // this block owns batch rows b2, b2+1
  const int tid = threadIdx.x;
  const int lane = tid & 63;
  const int wid = tid >> 6;   // 4 waves; wave w owns s-rows [32w, 32w+32)
  const int l15 = lane & 15;
  const int lh = lane >> 4;   // 0..3
  const int sw = (l15 & 7) << 3;  // XOR swizzle (elems) for 256B-stride tiles

  const __bf16* wqb = wbf;
  const __bf16* wkb = wbf + 8192;
  const __bf16* wvb = wbf + 16384;
  const __bf16* wob = wbf + 24576;  // [32][256] row-major

  const f32x4 fz = {0.f, 0.f, 0.f, 0.f};

  // ---------------- LayerNorm, both rows ----------------
  float xv[2][16];
  float mu[2], rs[2];
#pragma unroll
  for (int rr = 0; rr < 2; ++rr) {
    const float* xb = x + (b2 + rr) * INSZ;
    float s = 0.f, sq = 0.f;
#pragma unroll
    for (int i = 0; i < 4; ++i) {
      float4 a = ((const float4*)(xb + tid * 16))[i];
      xv[rr][4 * i] = a.x; xv[rr][4 * i + 1] = a.y;
      xv[rr][4 * i + 2] = a.z; xv[rr][4 * i + 3] = a.w;
    }
#pragma unroll
    for (int i = 0; i < 16; ++i) { s += xv[rr][i]; sq += xv[rr][i] * xv[rr][i]; }
#pragma unroll
    for (int o = 32; o > 0; o >>= 1) { s += __shfl_down(s, o); sq += __shfl_down(sq, o); }
    if (lane == 0) {
      float* red2 = (float*)&R[rr * ROWSZ + RD];
      red2[wid] = s; red2[4 + wid] = sq;
    }
  }
  __syncthreads();
#pragma unroll
  for (int rr = 0; rr < 2; ++rr) {
    const float* red2 = (const float*)&R[rr * ROWSZ + RD];
    float s = red2[0] + red2[1] + red2[2] + red2[3];
    float sq = red2[4] + red2[5] + red2[6] + red2[7];
    mu[rr] = s * (1.f / INSZ);
    float var = fmaxf(sq * (1.f / INSZ) - mu[rr] * mu[rr], 0.f);
    rs[rr] = rsqrtf(var + 1e-5f);
  }
  {
    int base = tid * 16;
#pragma unroll
    for (int i = 0; i < 4; ++i) {
      float4 g4 = ((const float4*)(gamma + base))[i];
      float4 b4 = ((const float4*)(beta + base))[i];
      float gg[4] = {g4.x, g4.y, g4.z, g4.w};
      float bb[4] = {b4.x, b4.y, b4.z, b4.w};
#pragma unroll
      for (int rr = 0; rr < 2; ++rr)
#pragma unroll
        for (int k = 0; k < 4; ++k) {
          int idx = base + 4 * i + k;
          float xn = (xv[rr][4 * i + k] - mu[rr]) * rs[rr] * gg[k] + bb[k];
          R[rr * ROWSZ + Q0 + (idx >> 5) * LDT + (idx & 31)] = (__bf16)xn;  // wave-local
        }
    }
  }
  // No barrier: xn rows are wave-local (written and read by the same wave).

  const int r0 = wid * 32;

  // xn fragments, head-invariant; xn (Q0 overlay) dies here.
  bf16x8 tA[2][2];
#pragma unroll
  for (int rr = 0; rr < 2; ++rr) {
    tA[rr][0] = *(const bf16x8*)&R[rr * ROWSZ + Q0 + (r0 + l15) * LDT + lh * 8];
    tA[rr][1] = *(const bf16x8*)&R[rr * ROWSZ + Q0 + (r0 + 16 + l15) * LDT + lh * 8];
  }

  // oacc[rr][mt][nt]: D[q][e'], q=r0+mt*16+lh*4+r, e'=nt*16+l15; seeded with bo.
  f32x4 oacc[2][2][2];
  {
    float b0 = bo[l15], b1 = bo[16 + l15];
#pragma unroll
    for (int rr = 0; rr < 2; ++rr)
#pragma unroll
      for (int mt = 0; mt < 2; ++mt) {
        oacc[rr][mt][0] = f32x4{b0, b0, b0, b0};
        oacc[rr][mt][1] = f32x4{b1, b1, b1, b1};
      }
  }

  bf16x8 ka[2][2];

  // Project head hh for BOTH rows; weight frags/biases loaded once.
  auto do_proj = [&](int hh, int qo, int vo) {
#pragma unroll
    for (int ft = 0; ft < 2; ++ft) {
      int f0 = hh * 32 + ft * 16;
      bf16x8 wqf = *(const bf16x8*)&wqb[(f0 + l15) * 32 + lh * 8];
      bf16x8 wkf = *(const bf16x8*)&wkb[(f0 + l15) * 32 + lh * 8];
      f32x4 bq4 = *(const f32x4*)&bq[f0 + lh * 4];
      f32x4 bk4 = *(const f32x4*)&bk[f0 + lh * 4];
#pragma unroll
      for (int r = 0; r < 4; ++r) bq4[r] *= CQ;
#pragma unroll
      for (int rr = 0; rr < 2; ++rr)
#pragma unroll
        for (int st = 0; st < 2; ++st) {
          bf16x8 tB = tA[rr][st];
          // D[f][s]: f = f0+lh*4+r, s = r0+st*16+l15; C seed = bias(f)
          f32x4 dq = __builtin_amdgcn_mfma_f32_16x16x32_bf16(wqf, tB, bq4, 0, 0, 0);
          f32x4 dk = __builtin_amdgcn_mfma_f32_16x16x32_bf16(wkf, tB, bk4, 0, 0, 0);
          bf16x4 pq, pk;
#pragma unroll
          for (int r = 0; r < 4; ++r) { pq[r] = (__bf16)dq[r]; pk[r] = (__bf16)dk[r]; }
          *(bf16x4*)&R[rr * ROWSZ + qo + (r0 + st * 16 + l15) * LDT + ft * 16 + lh * 4] = pq;
          *(bf16x4*)&R[rr * ROWSZ + KP + (r0 + st * 16 + l15) * LDT + ft * 16 + lh * 4] = pk;
        }
    }
#pragma unroll
    for (int nt = 0; nt < 2; ++nt) {
      int f0 = hh * 32 + nt * 16;
      bf16x8 wvf = *(const bf16x8*)&wvb[(f0 + l15) * 32 + lh * 8];
      float bvs = bv[f0 + l15];
      f32x4 bv4 = {bvs, bvs, bvs, bvs};
#pragma unroll
      for (int rr = 0; rr < 2; ++rr)
#pragma unroll
        for (int mt = 0; mt < 2; ++mt) {
          // D[s][f]: s = r0+mt*16+lh*4+r, f = f0+l15
          f32x4 dv = __builtin_amdgcn_mfma_f32_16x16x32_bf16(tA[rr][mt], wvf, bv4, 0, 0, 0);
          bf16x4 pv;
#pragma unroll
          for (int r = 0; r < 4; ++r) pv[r] = (__bf16)dv[r];
          *(bf16x4*)&R[rr * ROWSZ + vo + (nt * 16 + l15) * 128 +
                       ((r0 + mt * 16 + lh * 4) ^ sw)] = pv;
        }
    }
    // K fragments: wave-local rows, straight back into registers.
#pragma unroll
    for (int rr = 0; rr < 2; ++rr) {
      ka[rr][0] = *(const bf16x8*)&R[rr * ROWSZ + KP + (r0 + l15) * LDT + lh * 8];
      ka[rr][1] = *(const bf16x8*)&R[rr * ROWSZ + KP + (r0 + 16 + l15) * LDT + lh * 8];
    }
  };

  do_proj(0, Q0, V0);

  for (int h = 0; h < NH; ++h) {
    const int p = h & 1;
    const int qo = p ? Q1 : Q0;
    const int vo = p ? V1 : V0;
    __syncthreads();  // A: q[p] + vT[p] ready (both rows)

    // ---------- scoresT = K·q^T, both rows (independent MFMA streams) ----------
    // st_[rr][mt][it]: D[j][i], j = r0+mt*16+lh*4+r, i = it*16+l15
    f32x4 st_[2][2][8];
#pragma unroll
    for (int rr = 0; rr < 2; ++rr)
#pragma unroll
      for (int it = 0; it < 8; ++it) {
        bf16x8 qb8 = *(const bf16x8*)&R[rr * ROWSZ + qo + (it * 16 + l15) * LDT + lh * 8];
        st_[rr][0][it] = __builtin_amdgcn_mfma_f32_16x16x32_bf16(ka[rr][0], qb8, fz, 0, 0, 0);
        st_[rr][1][it] = __builtin_amdgcn_mfma_f32_16x16x32_bf16(ka[rr][1], qb8, fz, 0, 0, 0);
      }
    // ---------- project NEXT head (both rows) — fills scores MFMA latency ----------
    if (h < NH - 1) do_proj(h + 1, p ? Q0 : Q1, p ? V0 : V1);

    // ---------- softmax over query axis (m=0), both rows interleaved ----------
    float inv[2][2][4];
#pragma unroll
    for (int rr = 0; rr < 2; ++rr)
#pragma unroll
      for (int mt = 0; mt < 2; ++mt)
#pragma unroll
        for (int r = 0; r < 4; ++r) {
          float e0 = __builtin_amdgcn_exp2f(st_[rr][mt][0][r]);
          float e1 = __builtin_amdgcn_exp2f(st_[rr][mt][1][r]);
          float e2 = __builtin_amdgcn_exp2f(st_[rr][mt][2][r]);
          float e3 = __builtin_amdgcn_exp2f(st_[rr][mt][3][r]);
          float e4 = __builtin_amdgcn_exp2f(st_[rr][mt][4][r]);
          float e5 = __builtin_amdgcn_exp2f(st_[rr][mt][5][r]);
          float e6 = __builtin_amdgcn_exp2f(st_[rr][mt][6][r]);
          float e7 = __builtin_amdgcn_exp2f(st_[rr][mt][7][r]);
          st_[rr][mt][0][r] = e0; st_[rr][mt][1][r] = e1;
          st_[rr][mt][2][r] = e2; st_[rr][mt][3][r] = e3;
          st_[rr][mt][4][r] = e4; st_[rr][mt][5][r] = e5;
          st_[rr][mt][6][r] = e6; st_[rr][mt][7][r] = e7;
          float ssum = ((e0 + e1) + (e2 + e3)) + ((e4 + e5) + (e6 + e7));
          ssum = row_reduce_add16(ssum);
          inv[rr][mt][r] = __builtin_amdgcn_rcpf(ssum);
        }

    // ---------- P store: normalized, [query][key] swizzled, packed b64 ----------
#pragma unroll
    for (int rr = 0; rr < 2; ++rr)
#pragma unroll
      for (int mt = 0; mt < 2; ++mt)
#pragma unroll
        for (int it = 0; it < 8; ++it) {
          bf16x4 pp;
#pragma unroll
          for (int r = 0; r < 4; ++r) pp[r] = (__bf16)(st_[rr][mt][it][r] * inv[rr][mt][r]);
          *(bf16x4*)&R[rr * ROWSZ + PO + (it * 16 + l15) * 128 +
                       ((r0 + mt * 16 + lh * 4) ^ sw)] = pp;
        }
    __syncthreads();  // B: P ready (both rows)

    // ---------- PV + register outproj, both rows ----------
#pragma unroll
    for (int rr = 0; rr < 2; ++rr) {
      f32x4 p2[2][2];
#pragma unroll
      for (int i = 0; i < 2; ++i)
#pragma unroll
        for (int j = 0; j < 2; ++j) p2[i][j] = fz;
#pragma unroll
      for (int kc = 0; kc < 4; ++kc) {
        bf16x8 va0 = *(const bf16x8*)&R[rr * ROWSZ + vo + (l15) * 128 + ((kc * 32 + lh * 8) ^ sw)];
        bf16x8 va1 = *(const bf16x8*)&R[rr * ROWSZ + vo + (16 + l15) * 128 + ((kc * 32 + lh * 8) ^ sw)];
        bf16x8 pb0 = *(const bf16x8*)&R[rr * ROWSZ + PO + (r0 + l15) * 128 + ((kc * 32 + lh * 8) ^ sw)];
        bf16x8 pb1 = *(const bf16x8*)&R[rr * ROWSZ + PO + (r0 + 16 + l15) * 128 + ((kc * 32 + lh * 8) ^ sw)];
        p2[0][0] = __builtin_amdgcn_mfma_f32_16x16x32_bf16(va0, pb0, p2[0][0], 0, 0, 0);
        p2[0][1] = __builtin_amdgcn_mfma_f32_16x16x32_bf16(va0, pb1, p2[0][1], 0, 0, 0);
        p2[1][0] = __builtin_amdgcn_mfma_f32_16x16x32_bf16(va1, pb0, p2[1][0], 0, 0, 0);
        p2[1][1] = __builtin_amdgcn_mfma_f32_16x16x32_bf16(va1, pb1, p2[1][1], 0, 0, 0);
      }
      // outproj from registers (permuted-k: virtual k = lh*8+u <-> e=(u>=4)*16+lh*4+(u&3))
      bf16x8 pa0, pa1;
#pragma unroll
      for (int u = 0; u < 4; ++u) {
        pa0[u] = (__bf16)p2[0][0][u]; pa0[4 + u] = (__bf16)p2[1][0][u];
        pa1[u] = (__bf16)p2[0][1][u]; pa1[4 + u] = (__bf16)p2[1][1][u];
      }
      bf16x4 w0lo = *(const bf16x4*)&wob[(l15) * 256 + h * 32 + lh * 4];
      bf16x4 w0hi = *(const bf16x4*)&wob[(l15) * 256 + h * 32 + 16 + lh * 4];
      bf16x4 w1lo = *(const bf16x4*)&wob[(16 + l15) * 256 + h * 32 + lh * 4];
      bf16x4 w1hi = *(const bf16x4*)&wob[(16 + l15) * 256 + h * 32 + 16 + lh * 4];
      bf16x8 wof0, wof1;
#pragma unroll
      for (int u = 0; u < 4; ++u) {
        wof0[u] = w0lo[u]; wof0[4 + u] = w0hi[u];
        wof1[u] = w1lo[u]; wof1[4 + u] = w1hi[u];
      }
      oacc[rr][0][0] = __builtin_amdgcn_mfma_f32_16x16x32_bf16(pa0, wof0, oacc[rr][0][0], 0, 0, 0);
      oacc[rr][0][1] = __builtin_amdgcn_mfma_f32_16x16x32_bf16(pa0, wof1, oacc[rr][0][1], 0, 0, 0);
      oacc[rr][1][0] = __builtin_amdgcn_mfma_f32_16x16x32_bf16(pa1, wof0, oacc[rr][1][0], 0, 0, 0);
      oacc[rr][1][1] = __builtin_amdgcn_mfma_f32_16x16x32_bf16(pa1, wof1, oacc[rr][1][1], 0, 0, 0);
    }
    // No trailing barrier: next iteration's barrier A orders the cross-wave
    // buffers (opposite-parity q/vT; single-P re-store happens after next A).
  }

  // ---------------- epilogue: + x (bo already seeded), both rows ----------------
#pragma unroll
  for (int rr = 0; rr < 2; ++rr) {
    const float* xb = x + (b2 + rr) * INSZ;
#pragma unroll
    for (int mt = 0; mt < 2; ++mt)
#pragma unroll
      for (int nt = 0; nt < 2; ++nt)
#pragma unroll
        for (int r = 0; r < 4; ++r) {
          int s_ = r0 + mt * 16 + lh * 4 + r;
          int e_ = nt * 16 + l15;
          int idx = s_ * 32 + e_;
          out[(b2 + rr) * INSZ + idx] = oacc[rr][mt][nt][r] + xb[idx];
        }
  }
}

extern "C" void kernel_launch(void* const* d_in, const int* in_sizes, int n_in,
                              void* d_out, int out_size, void* d_ws, size_t ws_size,
                              hipStream_t stream) {
  const float* x = (const float*)d_in[0];
  const float* gamma = (const float*)d_in[1];
  const float* beta = (const float*)d_in[2];
  const float* wq = (const float*)d_in[3];
  const float* bq = (const float*)d_in[4];
  const float* wk = (const float*)d_in[5];
  const float* bk = (const float*)d_in[6];
  const float* wv = (const float*)d_in[7];
  const float* bv = (const float*)d_in[8];
  const float* wo = (const float*)d_in[9];
  const float* bo = (const float*)d_in[10];
  float* out = (float*)d_out;
  __bf16* wsb = (__bf16*)d_ws;

  cvt_w<<<128, 256, 0, stream>>>(wq, wk, wv, wo, wsb);
  mha_fused<<<BATCH / 2, TPB, 0, stream>>>(x, gamma, beta, bq, bk, bv, bo, wsb, out);
}

// Round 14
// 67.784 us; speedup vs baseline: 1.2601x; 1.2601x over previous
//
#include <hip/hip_runtime.h>

#define BATCH 1024
#define INSZ 4096
#define SQ 128
#define EM 32
#define NH 8
#define TPB 256

typedef __attribute__((ext_vector_type(8))) __bf16 bf16x8;
typedef __attribute__((ext_vector_type(4))) __bf16 bf16x4;
typedef __attribute__((ext_vector_type(4))) float f32x4;

// Unified LDS region, element offsets (bf16):
//   Q0 [0,5120)       q-stage parity0 [128][LDT=40], PERMUTED cols (xn overlay pre-loop)
//   Q1 [5120,10240)   q-stage parity1
//   V0 [10240,14336)  vT parity0 [32][128] swizzled
//   V1 [14336,18432)  vT parity1
//   PO [18432,34816)  P [128][128] swizzled — single buffer (A(h+1) separates
//                     PV(h) reads from P-store(h+1) writes)
//   RD [34816,34832)  LN reduction scratch
// Total 34832 elems = 69664 B -> 2 blocks/CU. K and prod NEVER touch LDS:
// K A-frags are packed straight from the K-proj MFMA output registers
// (permuted-k trick), prod feeds outproj via registers likewise.
#define LDT 40
#define Q0 0
#define Q1 5120
#define V0 10240
#define V1 14336
#define PO 18432
#define RD 34816

// 1/sqrt(32) * log2(e): folded into wq (cvt_w) and bq seed; scores emerge
// pre-scaled for exp2. Softmax over QUERY axis uses m=0 (shift-invariant;
// |scores| O(5) for LN'd data).
#define CQ 0.25505644061151687f

__global__ void cvt_w(const float* __restrict__ wq, const float* __restrict__ wk,
                      const float* __restrict__ wv, const float* __restrict__ wo,
                      __bf16* __restrict__ ws) {
  int i = blockIdx.x * blockDim.x + threadIdx.x;  // 0..32767
  const float* src = (i < 8192) ? wq : (i < 16384) ? wk : (i < 24576) ? wv : wo;
  float v = src[i & 8191];
  if (i < 8192) v *= CQ;
  ws[i] = (__bf16)v;
}

// 16-lane butterfly sum on the VALU pipe (DPP), no LDS traffic.
__device__ __forceinline__ float row_reduce_add16(float v) {
  int t;
  t = __builtin_amdgcn_update_dpp(0, __float_as_int(v), 0xB1, 0xF, 0xF, true);
  v += __int_as_float(t);
  t = __builtin_amdgcn_update_dpp(0, __float_as_int(v), 0x4E, 0xF, 0xF, true);
  v += __int_as_float(t);
  t = __builtin_amdgcn_update_dpp(0, __float_as_int(v), 0x141, 0xF, 0xF, true);
  v += __int_as_float(t);
  t = __builtin_amdgcn_update_dpp(0, __float_as_int(v), 0x140, 0xF, 0xF, true);
  v += __int_as_float(t);
  return v;
}

__global__ __launch_bounds__(TPB, 2) void mha_fused(
    const float* __restrict__ x, const float* __restrict__ gamma,
    const float* __restrict__ beta, const float* __restrict__ bq,
    const float* __restrict__ bk, const float* __restrict__ bv,
    const float* __restrict__ bo, const __bf16* __restrict__ wbf,
    float* __restrict__ out) {
  __shared__ __align__(16) __bf16 R[34832];  // 69664 B

  const int b = blockIdx.x;
  const int tid = threadIdx.x;
  const int lane = tid & 63;
  const int wid = tid >> 6;   // 4 waves; wave w owns s-rows [32w, 32w+32)
  const int l15 = lane & 15;
  const int lh = lane >> 4;   // 0..3
  const int sw = (l15 & 7) << 3;  // XOR swizzle (elems) for 256B-stride tiles

  const __bf16* wqb = wbf;
  const __bf16* wkb = wbf + 8192;
  const __bf16* wvb = wbf + 16384;
  const __bf16* wob = wbf + 24576;  // [32][256] row-major

  const float* xb = x + b * INSZ;
  const f32x4 fz = {0.f, 0.f, 0.f, 0.f};

  float* red2 = (float*)&R[RD];

  // ---------------- LayerNorm ----------------
  float xv[16];
  float s = 0.f, sq = 0.f;
#pragma unroll
  for (int i = 0; i < 4; ++i) {
    float4 a = ((const float4*)(xb + tid * 16))[i];
    xv[4 * i] = a.x; xv[4 * i + 1] = a.y; xv[4 * i + 2] = a.z; xv[4 * i + 3] = a.w;
  }
#pragma unroll
  for (int i = 0; i < 16; ++i) { s += xv[i]; sq += xv[i] * xv[i]; }
#pragma unroll
  for (int o = 32; o > 0; o >>= 1) { s += __shfl_down(s, o); sq += __shfl_down(sq, o); }
  if (lane == 0) { red2[wid] = s; red2[4 + wid] = sq; }
  __syncthreads();
  s = red2[0] + red2[1] + red2[2] + red2[3];
  sq = red2[4] + red2[5] + red2[6] + red2[7];
  const float mu = s * (1.f / INSZ);
  const float var = fmaxf(sq * (1.f / INSZ) - mu * mu, 0.f);
  const float rs = rsqrtf(var + 1e-5f);
  {
    int base = tid * 16;
#pragma unroll
    for (int i = 0; i < 4; ++i) {
      float4 g4 = ((const float4*)(gamma + base))[i];
      float4 b4 = ((const float4*)(beta + base))[i];
      float gg[4] = {g4.x, g4.y, g4.z, g4.w};
      float bb[4] = {b4.x, b4.y, b4.z, b4.w};
#pragma unroll
      for (int k = 0; k < 4; ++k) {
        int idx = base + 4 * i + k;
        float xn = (xv[4 * i + k] - mu) * rs * gg[k] + bb[k];
        R[Q0 + (idx >> 5) * LDT + (idx & 31)] = (__bf16)xn;  // wave-local rows
      }
    }
  }
  // No barrier: xn rows are wave-local (written and read by the same wave).

  const int r0 = wid * 32;

  // xn fragments are head-invariant: hoist to regs; xn (Q0 overlay) dies here.
  bf16x8 tA0 = *(const bf16x8*)&R[Q0 + (r0 + l15) * LDT + lh * 8];
  bf16x8 tA1 = *(const bf16x8*)&R[Q0 + (r0 + 16 + l15) * LDT + lh * 8];

  // oacc[mt][nt]: D[q][e'], q = r0+mt*16+lh*4+r, e' = nt*16+l15; seeded with bo.
  f32x4 oacc[2][2];
  {
    float b0 = bo[l15], b1 = bo[16 + l15];
#pragma unroll
    for (int mt = 0; mt < 2; ++mt) {
      oacc[mt][0] = f32x4{b0, b0, b0, b0};
      oacc[mt][1] = f32x4{b1, b1, b1, b1};
    }
  }

  // K A-fragments, packed straight from proj output regs (no LDS round-trip).
  bf16x8 ka0, ka1;

  // Project head hh into q[qo] (permuted cols), vT[vo]; K stays in registers.
  auto do_proj = [&](int hh, int qo, int vo) {
    bf16x4 pkk[2][2];  // [ft][st] K-proj bf16 outputs
#pragma unroll
    for (int ft = 0; ft < 2; ++ft) {
      int f0 = hh * 32 + ft * 16;
      bf16x8 wqf = *(const bf16x8*)&wqb[(f0 + l15) * 32 + lh * 8];
      bf16x8 wkf = *(const bf16x8*)&wkb[(f0 + l15) * 32 + lh * 8];
      f32x4 bq4 = *(const f32x4*)&bq[f0 + lh * 4];
      f32x4 bk4 = *(const f32x4*)&bk[f0 + lh * 4];
#pragma unroll
      for (int r = 0; r < 4; ++r) bq4[r] *= CQ;
#pragma unroll
      for (int st = 0; st < 2; ++st) {
        bf16x8 tB = (st == 0) ? tA0 : tA1;
        // D[f][s]: f = f0+lh*4+r, s = r0+st*16+l15; C seed = bias(f)
        f32x4 dq = __builtin_amdgcn_mfma_f32_16x16x32_bf16(wqf, tB, bq4, 0, 0, 0);
        f32x4 dk = __builtin_amdgcn_mfma_f32_16x16x32_bf16(wkf, tB, bk4, 0, 0, 0);
        bf16x4 pq, pk;
#pragma unroll
        for (int r = 0; r < 4; ++r) { pq[r] = (__bf16)dq[r]; pk[r] = (__bf16)dk[r]; }
        // q store, PERMUTED cols: physical col c = lh*8 + ft*4 + r encodes
        // f = ft*16 + lh*4 + r, so a b128 read at col lh*8 yields the
        // virtual-k order u -> f(u) = (u>=4)*16 + lh*4 + (u&3).
        *(bf16x4*)&R[qo + (r0 + st * 16 + l15) * LDT + lh * 8 + ft * 4] = pq;
        pkk[ft][st] = pk;
      }
    }
    // ka_st[u] = K[j = r0+st*16+l15][f(u)] — pack, zero extra VALU.
#pragma unroll
    for (int u = 0; u < 4; ++u) {
      ka0[u] = pkk[0][0][u]; ka0[4 + u] = pkk[1][0][u];
      ka1[u] = pkk[0][1][u]; ka1[4 + u] = pkk[1][1][u];
    }
#pragma unroll
    for (int nt = 0; nt < 2; ++nt) {
      int f0 = hh * 32 + nt * 16;
      bf16x8 wvf = *(const bf16x8*)&wvb[(f0 + l15) * 32 + lh * 8];
      float bvs = bv[f0 + l15];
      f32x4 bv4 = {bvs, bvs, bvs, bvs};
#pragma unroll
      for (int mt = 0; mt < 2; ++mt) {
        bf16x8 tA = (mt == 0) ? tA0 : tA1;
        // D[s][f]: s = r0+mt*16+lh*4+r, f = f0+l15
        f32x4 dv = __builtin_amdgcn_mfma_f32_16x16x32_bf16(tA, wvf, bv4, 0, 0, 0);
        bf16x4 pv;
#pragma unroll
        for (int r = 0; r < 4; ++r) pv[r] = (__bf16)dv[r];
        *(bf16x4*)&R[vo + (nt * 16 + l15) * 128 + ((r0 + mt * 16 + lh * 4) ^ sw)] = pv;
      }
    }
  };

  do_proj(0, Q0, V0);

  for (int h = 0; h < NH; ++h) {
    const int p = h & 1;
    const int qo = p ? Q1 : Q0;
    const int vo = p ? V1 : V0;
    __syncthreads();  // A: q[p] + vT[p] ready

    // ---------- scoresT = K·q^T : D[j][i], j=r0+..., i=it*16+l15 ----------
    // A-frags (ka0/ka1) already in registers; B-frags read b128 from the
    // permuted q layout (virtual-k orders agree — bijection over f).
    f32x4 st_[2][8];
    __builtin_amdgcn_s_setprio(1);
#pragma unroll
    for (int it = 0; it < 8; ++it) {
      bf16x8 qb8 = *(const bf16x8*)&R[qo + (it * 16 + l15) * LDT + lh * 8];
      st_[0][it] = __builtin_amdgcn_mfma_f32_16x16x32_bf16(ka0, qb8, fz, 0, 0, 0);
      st_[1][it] = __builtin_amdgcn_mfma_f32_16x16x32_bf16(ka1, qb8, fz, 0, 0, 0);
    }
    __builtin_amdgcn_s_setprio(0);

    // ---------- project NEXT head into opposite buffers (fills MFMA latency);
    // overwrites ka0/ka1 with head h+1's fragments AFTER scores(h) consumed them.
    if (h < NH - 1) do_proj(h + 1, p ? Q0 : Q1, p ? V0 : V1);

    // PV's vT fragments depend only on barrier A — prefetch during softmax.
    bf16x8 va[2][4];
#pragma unroll
    for (int kc = 0; kc < 4; ++kc) {
      va[0][kc] = *(const bf16x8*)&R[vo + (l15) * 128 + ((kc * 32 + lh * 8) ^ sw)];
      va[1][kc] = *(const bf16x8*)&R[vo + (16 + l15) * 128 + ((kc * 32 + lh * 8) ^ sw)];
    }

    // ---------- softmax over query axis (m=0): P = exp2(s'), DPP col sums ----------
    float inv[2][4];
#pragma unroll
    for (int mt = 0; mt < 2; ++mt)
#pragma unroll
      for (int r = 0; r < 4; ++r) {
        float ssum = 0.f;
#pragma unroll
        for (int it = 0; it < 8; ++it) {
          float e = __builtin_amdgcn_exp2f(st_[mt][it][r]);
          st_[mt][it][r] = e;
          ssum += e;
        }
        ssum = row_reduce_add16(ssum);
        inv[mt][r] = __builtin_amdgcn_rcpf(ssum);
      }

    // ---------- P store: normalized, [query][key] swizzled, packed b64 ----------
#pragma unroll
    for (int mt = 0; mt < 2; ++mt)
#pragma unroll
      for (int it = 0; it < 8; ++it) {
        bf16x4 pp;
#pragma unroll
        for (int r = 0; r < 4; ++r) pp[r] = (__bf16)(st_[mt][it][r] * inv[mt][r]);
        *(bf16x4*)&R[PO + (it * 16 + l15) * 128 + ((r0 + mt * 16 + lh * 4) ^ sw)] = pp;
      }
    __syncthreads();  // B: P ready

    // ---------- PV: D[e][q] = vT·P^T ----------
    f32x4 p2[2][2];
#pragma unroll
    for (int i = 0; i < 2; ++i)
#pragma unroll
      for (int j = 0; j < 2; ++j) p2[i][j] = fz;
    __builtin_amdgcn_s_setprio(1);
#pragma unroll
    for (int kc = 0; kc < 4; ++kc) {
      bf16x8 pb0 = *(const bf16x8*)&R[PO + (r0 + l15) * 128 + ((kc * 32 + lh * 8) ^ sw)];
      bf16x8 pb1 = *(const bf16x8*)&R[PO + (r0 + 16 + l15) * 128 + ((kc * 32 + lh * 8) ^ sw)];
      p2[0][0] = __builtin_amdgcn_mfma_f32_16x16x32_bf16(va[0][kc], pb0, p2[0][0], 0, 0, 0);
      p2[0][1] = __builtin_amdgcn_mfma_f32_16x16x32_bf16(va[0][kc], pb1, p2[0][1], 0, 0, 0);
      p2[1][0] = __builtin_amdgcn_mfma_f32_16x16x32_bf16(va[1][kc], pb0, p2[1][0], 0, 0, 0);
      p2[1][1] = __builtin_amdgcn_mfma_f32_16x16x32_bf16(va[1][kc], pb1, p2[1][1], 0, 0, 0);
    }
    __builtin_amdgcn_s_setprio(0);

    // ---------- outproj from registers (permuted-k, no prod LDS round-trip) ----------
    // virtual k = lh*8+u  <->  e = (u>=4)*16 + lh*4 + (u&3); A and B share it.
    // A(qt): pa[u] = prod[q=r0+qt*16+l15][e(u)] = p2[u>=4][qt][u&3]  (lane-local)
    // B(nt): wof[u] = wo[e'=nt*16+l15][h*32 + e(u)]  (two bf16x4 global loads)
    {
      bf16x8 pa0, pa1;
#pragma unroll
      for (int u = 0; u < 4; ++u) {
        pa0[u] = (__bf16)p2[0][0][u]; pa0[4 + u] = (__bf16)p2[1][0][u];
        pa1[u] = (__bf16)p2[0][1][u]; pa1[4 + u] = (__bf16)p2[1][1][u];
      }
      bf16x4 w0lo = *(const bf16x4*)&wob[(l15) * 256 + h * 32 + lh * 4];
      bf16x4 w0hi = *(const bf16x4*)&wob[(l15) * 256 + h * 32 + 16 + lh * 4];
      bf16x4 w1lo = *(const bf16x4*)&wob[(16 + l15) * 256 + h * 32 + lh * 4];
      bf16x4 w1hi = *(const bf16x4*)&wob[(16 + l15) * 256 + h * 32 + 16 + lh * 4];
      bf16x8 wof0, wof1;
#pragma unroll
      for (int u = 0; u < 4; ++u) {
        wof0[u] = w0lo[u]; wof0[4 + u] = w0hi[u];
        wof1[u] = w1lo[u]; wof1[4 + u] = w1hi[u];
      }
      oacc[0][0] = __builtin_amdgcn_mfma_f32_16x16x32_bf16(pa0, wof0, oacc[0][0], 0, 0, 0);
      oacc[0][1] = __builtin_amdgcn_mfma_f32_16x16x32_bf16(pa0, wof1, oacc[0][1], 0, 0, 0);
      oacc[1][0] = __builtin_amdgcn_mfma_f32_16x16x32_bf16(pa1, wof0, oacc[1][0], 0, 0, 0);
      oacc[1][1] = __builtin_amdgcn_mfma_f32_16x16x32_bf16(pa1, wof1, oacc[1][1], 0, 0, 0);
    }
    // No trailing barrier: next iteration's barrier A orders the cross-wave
    // buffers (opposite-parity q/vT; single-P re-store happens after A).
  }

  // ---------------- epilogue: + x (bo already seeded) ----------------
  // oacc[mt][nt][r]: row q = r0+mt*16+lh*4+r, col e' = nt*16+l15
#pragma unroll
  for (int mt = 0; mt < 2; ++mt)
#pragma unroll
    for (int nt = 0; nt < 2; ++nt)
#pragma unroll
      for (int r = 0; r < 4; ++r) {
        int s_ = r0 + mt * 16 + lh * 4 + r;
        int e_ = nt * 16 + l15;
        int idx = s_ * 32 + e_;
        out[b * INSZ + idx] = oacc[mt][nt][r] + xb[idx];
      }
}

extern "C" void kernel_launch(void* const* d_in, const int* in_sizes, int n_in,
                              void* d_out, int out_size, void* d_ws, size_t ws_size,
                              hipStream_t stream) {
  const float* x = (const float*)d_in[0];
  const float* gamma = (const float*)d_in[1];
  const float* beta = (const float*)d_in[2];
  const float* wq = (const float*)d_in[3];
  const float* bq = (const float*)d_in[4];
  const float* wk = (const float*)d_in[5];
  const float* bk = (const float*)d_in[6];
  const float* wv = (const float*)d_in[7];
  const float* bv = (const float*)d_in[8];
  const float* wo = (const float*)d_in[9];
  const float* bo = (const float*)d_in[10];
  float* out = (float*)d_out;
  __bf16* wsb = (__bf16*)d_ws;

  cvt_w<<<128, 256, 0, stream>>>(wq, wk, wv, wo, wsb);
  mha_fused<<<BATCH, TPB, 0, stream>>>(x, gamma, beta, bq, bk, bv, bo, wsb, out);
}